// Round 5
// baseline (894.673 us; speedup 1.0000x reference)
//
#include <hip/hip_runtime.h>
#include <cstdint>

// B=16, C=64, H=W=256. Three 3x3 convs via bf16 MFMA implicit GEMM.
// Round 5: DW epilogue now stages f2 through LDS via global_load_lds
// (round 4's scattered 8B global reads were the latency bottleneck).
using short8  = __attribute__((ext_vector_type(8))) short;
using short4v = __attribute__((ext_vector_type(4))) short;
using f32x16  = __attribute__((ext_vector_type(16))) float;
using float4v = __attribute__((ext_vector_type(4))) float;
typedef unsigned short ushort_t;

__device__ __forceinline__ float lrelu(float x) { return x > 0.f ? x : 0.1f * x; }

__device__ __forceinline__ ushort_t f2bf(float f) {
    union { float f; unsigned u; } v; v.f = f;
    unsigned r = (v.u + 0x7FFFu + ((v.u >> 16) & 1u)) >> 16;
    return (ushort_t)r;
}
__device__ __forceinline__ float bf2f(ushort_t b) {
    union { unsigned u; float f; } v; v.u = ((unsigned)b) << 16; return v.f;
}

// async 16B global -> LDS (dest = wave-uniform base + lane*16)
__device__ __forceinline__ void gload_lds16(const ushort_t* g, ushort_t* l) {
    __builtin_amdgcn_global_load_lds(
        (const __attribute__((address_space(1))) void*)g,
        (__attribute__((address_space(3))) void*)l, 16, 0, 0);
}

// ---------------------------------------------------------------------------
// Tiny branch: mv[b][c]; kern transposed to ktr[b][tap][c].
// ---------------------------------------------------------------------------
__global__ void k_tiny(const float* __restrict__ t, const float* __restrict__ tW1,
                       const float* __restrict__ tW2, const float* __restrict__ kW1,
                       const float* __restrict__ kW2, float* __restrict__ mv,
                       float* __restrict__ ktr) {
    int b = blockIdx.x;
    int c = threadIdx.x;  // 64
    __shared__ float h1[64], g1[64];
    float ts = t[b];
    h1[c] = lrelu(ts * tW1[c]);
    g1[c] = lrelu(ts * kW1[c]);
    __syncthreads();
    float s = 0.f;
    for (int j = 0; j < 64; ++j) s = fmaf(tW2[c * 64 + j], h1[j], s);
    mv[b * 64 + c] = 1.f / (1.f + expf(-s));
    for (int q = 0; q < 9; ++q) {
        float s2 = 0.f;
        for (int j = 0; j < 64; ++j) s2 = fmaf(kW2[(c * 9 + q) * 64 + j], g1[j], s2);
        ktr[b * 576 + q * 64 + c] = lrelu(s2);
    }
}

// ---------------------------------------------------------------------------
// Zero row buffer (edge-redirect source for staging).
// ---------------------------------------------------------------------------
__global__ void k_zrow(ushort_t* __restrict__ z) {
    int i = blockIdx.x * 256 + threadIdx.x;  // 2048 threads, 16384 shorts
    *(short8*)(z + (size_t)i * 8) = (short8)0;
}

// ---------------------------------------------------------------------------
// Pack three 64x64x3x3 weight tensors into MFMA A-fragment order (bf16).
// flat = (((t*2+ch)*2+kc)*2+ct)*512 + lane*8 + j
//   = W[co = ct*32 + (lane&31)][ci = ch*32 + kc*16 + (lane>>5)*8 + j], tap t
// ---------------------------------------------------------------------------
__global__ void k_pack(const float* __restrict__ w1, const float* __restrict__ w2,
                       const float* __restrict__ w3, ushort_t* __restrict__ wp) {
    int idx = blockIdx.x * 256 + threadIdx.x;
    if (idx >= 3 * 36864) return;
    int conv = idx / 36864, r = idx % 36864;
    const float* W = conv == 0 ? w1 : (conv == 1 ? w2 : w3);
    int j = r & 7, lane = (r >> 3) & 63, ct = (r >> 9) & 1, kc = (r >> 10) & 1,
        ch = (r >> 11) & 1, t = r >> 12;
    int co = ct * 32 + (lane & 31);
    int ci = ch * 32 + kc * 16 + (lane >> 5) * 8 + j;
    wp[idx] = f2bf(W[(co * 64 + ci) * 9 + t]);
}

// ---------------------------------------------------------------------------
// Transpose x: fp32 NCHW -> bf16 NHWC (width-256 rows). Block = (b,h).
// ---------------------------------------------------------------------------
__global__ __launch_bounds__(256) void k_tr(const float* __restrict__ x,
                                            ushort_t* __restrict__ xbf) {
    int bid = blockIdx.x;
    int h = bid & 255, b = bid >> 8;
    int t = threadIdx.x;
    for (int it = 0; it < 8; ++it) {
        int idx = t + it * 256;  // (w, g)
        int g = idx & 7, w = idx >> 3;
        const float* src = x + (((size_t)(b * 64 + g * 8) * 256 + h) * 256 + w);
        short8 v;
#pragma unroll
        for (int j = 0; j < 8; ++j) v[j] = (short)f2bf(src[(size_t)j * 65536]);
        *(short8*)(xbf + (((size_t)(b * 256 + h) * 256 + w) * 64 + g * 8)) = v;
    }
}

// ---------------------------------------------------------------------------
// 3x3 conv 64->64 via v_mfma_f32_32x32x16_bf16.
// Block = (b, h) after XCD swizzle: 4 waves, each 64 c_out x 64 pixels.
// LDS: 3136 slots x 16B = 50176 B (3 rows x 130 pixel-pairs x 8 slots + pad).
// Staging: global_load_lds, swizzle folded into per-lane source address:
//   slot S -> r=S/1040, m=(S%1040)>>3, sl=S&7; s'=sl^(m&7); p=2m+(s'>>2); g=s'&3
//   source = row[h+r-1][ws=p-1][cbase+g*8] ; edges -> zero row
// DW=true: epilogue re-stages f2 rows into the same LDS (2 chunks) and
// computes 9-tap dynamic depthwise + mv gate from ds_read_b64.
// ---------------------------------------------------------------------------
template <bool LEAKY, bool DW>
__global__ __launch_bounds__(256, 3) void k_conv(const ushort_t* __restrict__ in,
                                                 const ushort_t* __restrict__ zv,
                                                 const ushort_t* __restrict__ wp,
                                                 const float* __restrict__ bias,
                                                 const ushort_t* __restrict__ f2,
                                                 const float* __restrict__ ktr,
                                                 const float* __restrict__ mv,
                                                 void* __restrict__ outp) {
    __shared__ __align__(16) ushort_t xs[3136 * 8];  // 50176 B
    const int tid = threadIdx.x;
    const int lane = tid & 63;
    const int wv = tid >> 6;
    const unsigned bid = blockIdx.x;
    const unsigned L = (bid & 7u) * 512u + (bid >> 3);  // XCD-contiguous h
    const int h = L & 255, b = L >> 8;
    const int l31 = lane & 31, lhi = lane >> 5;
    const int pw0 = wv * 64;

    const ushort_t* rb0 = (h > 0)   ? in + ((size_t)(b * 256 + h - 1)) * 16384 : zv;
    const ushort_t* rb1 =             in + ((size_t)(b * 256 + h)) * 16384;
    const ushort_t* rb2 = (h < 255) ? in + ((size_t)(b * 256 + h + 1)) * 16384 : zv;

    f32x16 acc[2][2];
#pragma unroll
    for (int a = 0; a < 2; ++a)
#pragma unroll
        for (int c = 0; c < 2; ++c) acc[a][c] = (f32x16)0.0f;

    for (int ch = 0; ch < 2; ++ch) {
        __syncthreads();  // previous-chunk readers done
#pragma unroll
        for (int it = 0; it < 13; ++it) {
            int base = it * 256 + wv * 64;  // wave-uniform
            if (base < 3120) {
                int S = base + lane;
                S = S < 3120 ? S : 3119;
                int r = (S >= 2080) ? 2 : (S >= 1040 ? 1 : 0);
                int rem = S - r * 1040;
                int m = rem >> 3, sl = rem & 7;
                int sp = sl ^ (m & 7);
                int p = 2 * m + (sp >> 2), g = sp & 3;
                int ws = p - 1;
                bool edge = (unsigned)ws >= 256u;
                const ushort_t* rp = (r == 0) ? rb0 : (r == 1 ? rb1 : rb2);
                const ushort_t* src =
                    edge ? zv : (rp + ws * 64 + ch * 32 + g * 8);
                gload_lds16(src, xs + (size_t)base * 8);
            }
        }
        asm volatile("s_waitcnt vmcnt(0)" ::: "memory");
        __syncthreads();

#pragma unroll
        for (int t = 0; t < 9; ++t) {
            const int dw = t % 3;
#pragma unroll
            for (int kc = 0; kc < 2; ++kc) {
                const ushort_t* wpf = wp + (((((t * 2 + ch) * 2 + kc) * 2) * 64 + lane) * 8);
                short8 a0 = *(const short8*)(wpf);
                short8 a1 = *(const short8*)(wpf + 512);
                const int g = kc * 2 + lhi;
                const int rr = t / 3;
#pragma unroll
                for (int pt = 0; pt < 2; ++pt) {
                    int p = pw0 + pt * 32 + l31 + dw;
                    int slot = ((p & 1) * 4 + g) ^ ((p >> 1) & 7);
                    short8 bf = *(const short8*)(xs + (((size_t)rr * 130 + (p >> 1)) * 8 + slot) * 8);
                    acc[0][pt] = __builtin_amdgcn_mfma_f32_32x32x16_bf16(a0, bf, acc[0][pt], 0, 0, 0);
                    acc[1][pt] = __builtin_amdgcn_mfma_f32_32x32x16_bf16(a1, bf, acc[1][pt], 0, 0, 0);
                }
            }
        }
    }

    // Epilogue. D layout: col(pix)=lane&31, row(co)=(reg&3)+8*(reg>>2)+4*(lane>>5)
    const int co_b = 4 * lhi;
    if (!DW) {
        ushort_t* outb = (ushort_t*)outp + ((size_t)(b * 256 + h)) * 16384;
#pragma unroll
        for (int ct = 0; ct < 2; ++ct)
#pragma unroll
            for (int pt = 0; pt < 2; ++pt) {
                int pix = pw0 + pt * 32 + l31;
                ushort_t* po = outb + (size_t)pix * 64 + ct * 32 + co_b;
#pragma unroll
                for (int q = 0; q < 4; ++q) {
                    float4v bv = *(const float4v*)(bias + ct * 32 + co_b + 8 * q);
                    short4v sv;
#pragma unroll
                    for (int m = 0; m < 4; ++m) {
                        float v = acc[ct][pt][q * 4 + m] + bv[m];
                        if (LEAKY) v = lrelu(v);
                        sv[m] = (short)f2bf(v);
                    }
                    *(short4v*)(po + 8 * q) = sv;
                }
            }
    } else {
        // Fused final: out = dw(f2,kern)*mv + conv + bias, fp32 NCHW.
        float* po = (float*)outp;
        const ushort_t* fr0 = (h > 0)   ? f2 + ((size_t)(b * 256 + h - 1)) * 16384 : zv;
        const ushort_t* fr1 =             f2 + ((size_t)(b * 256 + h)) * 16384;
        const ushort_t* fr2 = (h < 255) ? f2 + ((size_t)(b * 256 + h + 1)) * 16384 : zv;

        for (int ct = 0; ct < 2; ++ct) {
            __syncthreads();  // previous xs readers done
#pragma unroll
            for (int it = 0; it < 13; ++it) {
                int base = it * 256 + wv * 64;
                if (base < 3120) {
                    int S = base + lane;
                    S = S < 3120 ? S : 3119;
                    int r = (S >= 2080) ? 2 : (S >= 1040 ? 1 : 0);
                    int rem = S - r * 1040;
                    int m = rem >> 3, sl = rem & 7;
                    int sp = sl ^ (m & 7);
                    int p = 2 * m + (sp >> 2), g = sp & 3;
                    int ws = p - 1;
                    bool edge = (unsigned)ws >= 256u;
                    const ushort_t* rp = (r == 0) ? fr0 : (r == 1 ? fr1 : fr2);
                    const ushort_t* src =
                        edge ? zv : (rp + ws * 64 + ct * 32 + g * 8);
                    gload_lds16(src, xs + (size_t)base * 8);
                }
            }
            asm volatile("s_waitcnt vmcnt(0)" ::: "memory");
            __syncthreads();

#pragma unroll
            for (int q = 0; q < 4; ++q) {
                // lane's 4 consecutive channels: co = ct*32 + 4*lhi + 8*q + m
                const int cb4 = ct * 32 + co_b + 8 * q;
                float4v kv[9];
#pragma unroll
                for (int t9 = 0; t9 < 9; ++t9)
                    kv[t9] = *(const float4v*)(ktr + b * 576 + t9 * 64 + cb4);
                float4v mvv = *(const float4v*)(mv + b * 64 + cb4);
                float4v bv = *(const float4v*)(bias + cb4);
#pragma unroll
                for (int pt = 0; pt < 2; ++pt) {
                    int pix = pw0 + pt * 32 + l31;
                    float dw4[4] = {0.f, 0.f, 0.f, 0.f};
#pragma unroll
                    for (int r = 0; r < 3; ++r)
#pragma unroll
                        for (int dx = 0; dx < 3; ++dx) {
                            int p = pix + dx;  // LDS pixel index (ws = p-1)
                            int slot = ((p & 1) * 4 + q) ^ ((p >> 1) & 7);
                            short4v sv = *(const short4v*)(
                                xs + (((size_t)r * 130 + (p >> 1)) * 8 + slot) * 8 + 4 * lhi);
                            float4v kq = kv[r * 3 + dx];
#pragma unroll
                            for (int m = 0; m < 4; ++m)
                                dw4[m] = fmaf(kq[m], bf2f((ushort_t)sv[m]), dw4[m]);
                        }
#pragma unroll
                    for (int m = 0; m < 4; ++m) {
                        float v = fmaf(dw4[m], mvv[m], acc[ct][pt][q * 4 + m] + bv[m]);
                        po[((size_t)(b * 64 + cb4 + m) << 16) + h * 256 + pix] = v;
                    }
                }
            }
        }
    }
}

// ---------------------------------------------------------------------------
extern "C" void kernel_launch(void* const* d_in, const int* in_sizes, int n_in,
                              void* d_out, int out_size, void* d_ws, size_t ws_size,
                              hipStream_t stream) {
    const float* x   = (const float*)d_in[0];
    const float* t   = (const float*)d_in[1];
    const float* tW1 = (const float*)d_in[2];
    const float* tW2 = (const float*)d_in[3];
    const float* fW1 = (const float*)d_in[4];
    const float* fb1 = (const float*)d_in[5];
    const float* fW2 = (const float*)d_in[6];
    const float* fb2 = (const float*)d_in[7];
    const float* kW1 = (const float*)d_in[8];
    const float* kW2 = (const float*)d_in[9];
    const float* cW  = (const float*)d_in[10];
    const float* cb  = (const float*)d_in[11];

    // ws: [mv 4K][ktr 36K @4096][wp 216K @65536][zv 32K @294912]
    //     [xbf 128MB @512K][f2bf 128MB @512K+128MB]  total ~256.5MB
    char* ws = (char*)d_ws;
    float*    mv    = (float*)ws;
    float*    ktr   = (float*)(ws + 4096);
    ushort_t* wp    = (ushort_t*)(ws + 65536);
    ushort_t* zv    = (ushort_t*)(ws + 294912);
    ushort_t* xbf   = (ushort_t*)(ws + (512u << 10));
    ushort_t* f2bf_ = (ushort_t*)(ws + (512u << 10) + ((size_t)128 << 20));
    ushort_t* f1bf  = (ushort_t*)d_out;  // scratch inside d_out
    float*    out   = (float*)d_out;

    k_tiny<<<dim3(16), dim3(64), 0, stream>>>(t, tW1, tW2, kW1, kW2, mv, ktr);
    k_zrow<<<dim3(8), dim3(256), 0, stream>>>(zv);
    k_pack<<<dim3((3 * 36864 + 255) / 256), dim3(256), 0, stream>>>(fW1, fW2, cW, wp);
    k_tr<<<dim3(4096), dim3(256), 0, stream>>>(x, xbf);

    k_conv<true, false><<<dim3(4096), dim3(256), 0, stream>>>(
        xbf, zv, wp, fb1, nullptr, nullptr, nullptr, (void*)f1bf);
    k_conv<true, false><<<dim3(4096), dim3(256), 0, stream>>>(
        f1bf, zv, wp + 36864, fb2, nullptr, nullptr, nullptr, (void*)f2bf_);
    k_conv<false, true><<<dim3(4096), dim3(256), 0, stream>>>(
        xbf, zv, wp + 2 * 36864, cb, f2bf_, ktr, mv, (void*)out);
}

// Round 6
// 673.928 us; speedup vs baseline: 1.3276x; 1.3276x over previous
//
#include <hip/hip_runtime.h>
#include <cstdint>

// B=16, C=64, H=W=256. Three 3x3 convs via bf16 MFMA implicit GEMM.
// Round 6: de-fuse depthwise from conv3. conv2 -> f2 bf16 NCHW; conv3 is a
// pure conv writing fp32 NCHW into d_out; new high-occupancy k_fin does the
// 9-tap dynamic depthwise (mv folded into kern) as a coalesced NCHW stencil.
using short8  = __attribute__((ext_vector_type(8))) short;
using short4v = __attribute__((ext_vector_type(4))) short;
using f32x16  = __attribute__((ext_vector_type(16))) float;
using float4v = __attribute__((ext_vector_type(4))) float;
typedef unsigned short ushort_t;

__device__ __forceinline__ float lrelu(float x) { return x > 0.f ? x : 0.1f * x; }

__device__ __forceinline__ ushort_t f2bf(float f) {
    union { float f; unsigned u; } v; v.f = f;
    unsigned r = (v.u + 0x7FFFu + ((v.u >> 16) & 1u)) >> 16;
    return (ushort_t)r;
}
__device__ __forceinline__ float bf2f(ushort_t b) {
    union { unsigned u; float f; } v; v.u = ((unsigned)b) << 16; return v.f;
}

// async 16B global -> LDS (dest = wave-uniform base + lane*16)
__device__ __forceinline__ void gload_lds16(const ushort_t* g, ushort_t* l) {
    __builtin_amdgcn_global_load_lds(
        (const __attribute__((address_space(1))) void*)g,
        (__attribute__((address_space(3))) void*)l, 16, 0, 0);
}

// ---------------------------------------------------------------------------
// Tiny branch: ktr[b][tap][c] = leaky(kern) * sigmoid-gate (mv folded in).
// ---------------------------------------------------------------------------
__global__ void k_tiny(const float* __restrict__ t, const float* __restrict__ tW1,
                       const float* __restrict__ tW2, const float* __restrict__ kW1,
                       const float* __restrict__ kW2, float* __restrict__ ktr) {
    int b = blockIdx.x;
    int c = threadIdx.x;  // 64
    __shared__ float h1[64], g1[64];
    float ts = t[b];
    h1[c] = lrelu(ts * tW1[c]);
    g1[c] = lrelu(ts * kW1[c]);
    __syncthreads();
    float s = 0.f;
    for (int j = 0; j < 64; ++j) s = fmaf(tW2[c * 64 + j], h1[j], s);
    float mvv = 1.f / (1.f + expf(-s));
    for (int q = 0; q < 9; ++q) {
        float s2 = 0.f;
        for (int j = 0; j < 64; ++j) s2 = fmaf(kW2[(c * 9 + q) * 64 + j], g1[j], s2);
        ktr[b * 576 + q * 64 + c] = lrelu(s2) * mvv;
    }
}

// ---------------------------------------------------------------------------
// Zero row buffer (edge-redirect source for staging).
// ---------------------------------------------------------------------------
__global__ void k_zrow(ushort_t* __restrict__ z) {
    int i = blockIdx.x * 256 + threadIdx.x;  // 2048 threads, 16384 shorts
    *(short8*)(z + (size_t)i * 8) = (short8)0;
}

// ---------------------------------------------------------------------------
// Pack three 64x64x3x3 weight tensors into MFMA A-fragment order (bf16).
// flat = (((t*2+ch)*2+kc)*2+ct)*512 + lane*8 + j
//   = W[co = ct*32 + (lane&31)][ci = ch*32 + kc*16 + (lane>>5)*8 + j], tap t
// ---------------------------------------------------------------------------
__global__ void k_pack(const float* __restrict__ w1, const float* __restrict__ w2,
                       const float* __restrict__ w3, ushort_t* __restrict__ wp) {
    int idx = blockIdx.x * 256 + threadIdx.x;
    if (idx >= 3 * 36864) return;
    int conv = idx / 36864, r = idx % 36864;
    const float* W = conv == 0 ? w1 : (conv == 1 ? w2 : w3);
    int j = r & 7, lane = (r >> 3) & 63, ct = (r >> 9) & 1, kc = (r >> 10) & 1,
        ch = (r >> 11) & 1, t = r >> 12;
    int co = ct * 32 + (lane & 31);
    int ci = ch * 32 + kc * 16 + (lane >> 5) * 8 + j;
    wp[idx] = f2bf(W[(co * 64 + ci) * 9 + t]);
}

// ---------------------------------------------------------------------------
// Transpose x: fp32 NCHW -> bf16 NHWC (width-256 rows). Block = (b,h).
// ---------------------------------------------------------------------------
__global__ __launch_bounds__(256) void k_tr(const float* __restrict__ x,
                                            ushort_t* __restrict__ xbf) {
    int bid = blockIdx.x;
    int h = bid & 255, b = bid >> 8;
    int t = threadIdx.x;
    for (int it = 0; it < 8; ++it) {
        int idx = t + it * 256;  // (w, g)
        int g = idx & 7, w = idx >> 3;
        const float* src = x + (((size_t)(b * 64 + g * 8) * 256 + h) * 256 + w);
        short8 v;
#pragma unroll
        for (int j = 0; j < 8; ++j) v[j] = (short)f2bf(src[(size_t)j * 65536]);
        *(short8*)(xbf + (((size_t)(b * 256 + h) * 256 + w) * 64 + g * 8)) = v;
    }
}

// ---------------------------------------------------------------------------
// 3x3 conv 64->64 via v_mfma_f32_32x32x16_bf16.
// Block = (b, h) after XCD swizzle: 4 waves, each 64 c_out x 64 pixels.
// LDS: 3136 slots x 16B = 50176 B (3 rows x 130 pixel-pairs x 8 slots + pad).
// Staging: global_load_lds, swizzle folded into per-lane source address.
// OMODE: 0 = bf16 NHWC, 1 = bf16 NCHW, 2 = fp32 NCHW.
// ---------------------------------------------------------------------------
template <bool LEAKY, int OMODE>
__global__ __launch_bounds__(256, 3) void k_conv(const ushort_t* __restrict__ in,
                                                 const ushort_t* __restrict__ zv,
                                                 const ushort_t* __restrict__ wp,
                                                 const float* __restrict__ bias,
                                                 void* __restrict__ outp) {
    __shared__ __align__(16) ushort_t xs[3136 * 8];  // 50176 B
    const int tid = threadIdx.x;
    const int lane = tid & 63;
    const int wv = tid >> 6;
    const unsigned bid = blockIdx.x;
    const unsigned L = (bid & 7u) * 512u + (bid >> 3);  // XCD-contiguous h
    const int h = L & 255, b = L >> 8;
    const int l31 = lane & 31, lhi = lane >> 5;
    const int pw0 = wv * 64;

    const ushort_t* rb0 = (h > 0)   ? in + ((size_t)(b * 256 + h - 1)) * 16384 : zv;
    const ushort_t* rb1 =             in + ((size_t)(b * 256 + h)) * 16384;
    const ushort_t* rb2 = (h < 255) ? in + ((size_t)(b * 256 + h + 1)) * 16384 : zv;

    f32x16 acc[2][2];
#pragma unroll
    for (int a = 0; a < 2; ++a)
#pragma unroll
        for (int c = 0; c < 2; ++c) acc[a][c] = (f32x16)0.0f;

    for (int ch = 0; ch < 2; ++ch) {
        __syncthreads();  // previous-chunk readers done
#pragma unroll
        for (int it = 0; it < 13; ++it) {
            int base = it * 256 + wv * 64;  // wave-uniform
            if (base < 3120) {
                int S = base + lane;
                S = S < 3120 ? S : 3119;
                int r = (S >= 2080) ? 2 : (S >= 1040 ? 1 : 0);
                int rem = S - r * 1040;
                int m = rem >> 3, sl = rem & 7;
                int sp = sl ^ (m & 7);
                int p = 2 * m + (sp >> 2), g = sp & 3;
                int ws = p - 1;
                bool edge = (unsigned)ws >= 256u;
                const ushort_t* rp = (r == 0) ? rb0 : (r == 1 ? rb1 : rb2);
                const ushort_t* src =
                    edge ? zv : (rp + ws * 64 + ch * 32 + g * 8);
                gload_lds16(src, xs + (size_t)base * 8);
            }
        }
        asm volatile("s_waitcnt vmcnt(0)" ::: "memory");
        __syncthreads();

#pragma unroll
        for (int t = 0; t < 9; ++t) {
            const int dw = t % 3;
#pragma unroll
            for (int kc = 0; kc < 2; ++kc) {
                const ushort_t* wpf = wp + (((((t * 2 + ch) * 2 + kc) * 2) * 64 + lane) * 8);
                short8 a0 = *(const short8*)(wpf);
                short8 a1 = *(const short8*)(wpf + 512);
                const int g = kc * 2 + lhi;
                const int rr = t / 3;
#pragma unroll
                for (int pt = 0; pt < 2; ++pt) {
                    int p = pw0 + pt * 32 + l31 + dw;
                    int slot = ((p & 1) * 4 + g) ^ ((p >> 1) & 7);
                    short8 bf = *(const short8*)(xs + (((size_t)rr * 130 + (p >> 1)) * 8 + slot) * 8);
                    acc[0][pt] = __builtin_amdgcn_mfma_f32_32x32x16_bf16(a0, bf, acc[0][pt], 0, 0, 0);
                    acc[1][pt] = __builtin_amdgcn_mfma_f32_32x32x16_bf16(a1, bf, acc[1][pt], 0, 0, 0);
                }
            }
        }
    }

    // Epilogue. D layout: col(pix)=lane&31, row(co)=(reg&3)+8*(reg>>2)+4*(lane>>5)
    const int co_b = 4 * lhi;
    if (OMODE == 0) {
        ushort_t* outb = (ushort_t*)outp + ((size_t)(b * 256 + h)) * 16384;
#pragma unroll
        for (int ct = 0; ct < 2; ++ct)
#pragma unroll
            for (int pt = 0; pt < 2; ++pt) {
                int pix = pw0 + pt * 32 + l31;
                ushort_t* po = outb + (size_t)pix * 64 + ct * 32 + co_b;
#pragma unroll
                for (int q = 0; q < 4; ++q) {
                    float4v bv = *(const float4v*)(bias + ct * 32 + co_b + 8 * q);
                    short4v sv;
#pragma unroll
                    for (int m = 0; m < 4; ++m) {
                        float v = acc[ct][pt][q * 4 + m] + bv[m];
                        if (LEAKY) v = lrelu(v);
                        sv[m] = (short)f2bf(v);
                    }
                    *(short4v*)(po + 8 * q) = sv;
                }
            }
    } else if (OMODE == 1) {
        // bf16 NCHW: per (c), half-wave writes 32 consecutive pix (64 B).
        ushort_t* pb = (ushort_t*)outp + (((size_t)b * 64) << 16) + h * 256;
#pragma unroll
        for (int ct = 0; ct < 2; ++ct)
#pragma unroll
            for (int pt = 0; pt < 2; ++pt) {
                int pix = pw0 + pt * 32 + l31;
#pragma unroll
                for (int q = 0; q < 4; ++q) {
                    float4v bv = *(const float4v*)(bias + ct * 32 + co_b + 8 * q);
#pragma unroll
                    for (int m = 0; m < 4; ++m) {
                        int c = ct * 32 + co_b + 8 * q + m;
                        float v = acc[ct][pt][q * 4 + m] + bv[m];
                        if (LEAKY) v = lrelu(v);
                        pb[((size_t)c << 16) + pix] = f2bf(v);
                    }
                }
            }
    } else {
        // fp32 NCHW (+bias)
        float* pb = (float*)outp + (((size_t)b * 64) << 16) + h * 256;
#pragma unroll
        for (int ct = 0; ct < 2; ++ct)
#pragma unroll
            for (int pt = 0; pt < 2; ++pt) {
                int pix = pw0 + pt * 32 + l31;
#pragma unroll
                for (int q = 0; q < 4; ++q) {
                    float4v bv = *(const float4v*)(bias + ct * 32 + co_b + 8 * q);
#pragma unroll
                    for (int m = 0; m < 4; ++m) {
                        int c = ct * 32 + co_b + 8 * q + m;
                        float v = acc[ct][pt][q * 4 + m] + bv[m];
                        if (LEAKY) v = lrelu(v);
                        pb[((size_t)c << 16) + pix] = v;
                    }
                }
            }
    }
}

// ---------------------------------------------------------------------------
// Final depthwise: out[b][c][h][w] += sum_tap ktr[b][tap][c] * f2[b][c][h'][w']
// (ktr already includes the mv gate; out already holds conv(x,cW)+cb.)
// Block = (b, c, 8-row band); f2 is bf16 NCHW. 5.4 KB LDS -> ~8 blocks/CU.
// ---------------------------------------------------------------------------
__global__ __launch_bounds__(256) void k_fin(const ushort_t* __restrict__ f2,
                                             const float* __restrict__ ktr,
                                             float* __restrict__ out) {
    __shared__ __align__(16) ushort_t s[10 * 272];
    const unsigned bid = blockIdx.x;
    const unsigned L = (bid & 7u) * 4096u + (bid >> 3);  // bijective, 32768=8*4096
    const int hb = L & 31, c = (L >> 5) & 63, b = L >> 11;
    const int h0 = hb * 8;
    const int w = threadIdx.x;

    const ushort_t* f2c = f2 + (((size_t)(b * 64 + c)) << 16);
    // stage 10 rows (h0-1 .. h0+8), 16B-aligned at column offset 8
    for (int i = w; i < 320; i += 256) {
        int r = i >> 5, seg = i & 31;
        int hs = h0 - 1 + r;
        short8 v = (short8)0;
        if ((unsigned)hs < 256u) v = *(const short8*)(f2c + hs * 256 + seg * 8);
        *(short8*)(&s[r * 272 + 8 + seg * 8]) = v;
        if (seg == 0) s[r * 272 + 7] = 0;
        if (seg == 31) s[r * 272 + 264] = 0;
    }
    __syncthreads();

    float kv[9];
#pragma unroll
    for (int t9 = 0; t9 < 9; ++t9) kv[t9] = ktr[b * 576 + t9 * 64 + c];

    float lv[10], cv[10], rv[10];
#pragma unroll
    for (int r = 0; r < 10; ++r) {
        lv[r] = bf2f(s[r * 272 + 7 + w]);
        cv[r] = bf2f(s[r * 272 + 8 + w]);
        rv[r] = bf2f(s[r * 272 + 9 + w]);
    }

    float* ob = out + (((size_t)(b * 64 + c)) << 16) + h0 * 256 + w;
#pragma unroll
    for (int rr = 0; rr < 8; ++rr) {
        float dwv = 0.f;
#pragma unroll
        for (int r3 = 0; r3 < 3; ++r3) {
            dwv = fmaf(kv[r3 * 3 + 0], lv[rr + r3], dwv);
            dwv = fmaf(kv[r3 * 3 + 1], cv[rr + r3], dwv);
            dwv = fmaf(kv[r3 * 3 + 2], rv[rr + r3], dwv);
        }
        float* po = ob + rr * 256;
        *po = *po + dwv;
    }
}

// ---------------------------------------------------------------------------
extern "C" void kernel_launch(void* const* d_in, const int* in_sizes, int n_in,
                              void* d_out, int out_size, void* d_ws, size_t ws_size,
                              hipStream_t stream) {
    const float* x   = (const float*)d_in[0];
    const float* t   = (const float*)d_in[1];
    const float* tW1 = (const float*)d_in[2];
    const float* tW2 = (const float*)d_in[3];
    const float* fW1 = (const float*)d_in[4];
    const float* fb1 = (const float*)d_in[5];
    const float* fW2 = (const float*)d_in[6];
    const float* fb2 = (const float*)d_in[7];
    const float* kW1 = (const float*)d_in[8];
    const float* kW2 = (const float*)d_in[9];
    const float* cW  = (const float*)d_in[10];
    const float* cb  = (const float*)d_in[11];

    // ws: [ktr 36K @0][wp 216K @65536][zv 32K @294912]
    //     [xbf 128MB @512K][f2 bf16 NCHW 128MB @512K+128MB]  total ~256.5MB
    char* ws = (char*)d_ws;
    float*    ktr  = (float*)ws;
    ushort_t* wp   = (ushort_t*)(ws + 65536);
    ushort_t* zv   = (ushort_t*)(ws + 294912);
    ushort_t* xbf  = (ushort_t*)(ws + (512u << 10));
    ushort_t* f2n  = (ushort_t*)(ws + (512u << 10) + ((size_t)128 << 20));
    ushort_t* f1bf = (ushort_t*)d_out;  // scratch inside d_out (dead after conv2)
    float*    out  = (float*)d_out;

    k_tiny<<<dim3(16), dim3(64), 0, stream>>>(t, tW1, tW2, kW1, kW2, ktr);
    k_zrow<<<dim3(8), dim3(256), 0, stream>>>(zv);
    k_pack<<<dim3((3 * 36864 + 255) / 256), dim3(256), 0, stream>>>(fW1, fW2, cW, wp);
    k_tr<<<dim3(4096), dim3(256), 0, stream>>>(x, xbf);

    k_conv<true, 0><<<dim3(4096), dim3(256), 0, stream>>>(xbf, zv, wp, fb1, (void*)f1bf);
    k_conv<true, 1><<<dim3(4096), dim3(256), 0, stream>>>(f1bf, zv, wp + 36864, fb2, (void*)f2n);
    k_conv<false, 2><<<dim3(4096), dim3(256), 0, stream>>>(xbf, zv, wp + 2 * 36864, cb, (void*)out);
    k_fin<<<dim3(32768), dim3(256), 0, stream>>>(f2n, ktr, out);
}